// Round 14
// baseline (1460.489 us; speedup 1.0000x reference)
//
#include <hip/hip_runtime.h>

// ---------------- common types/helpers ----------------
typedef _Float16 h8 __attribute__((ext_vector_type(8)));   // 8 fp16 (16 B)
typedef _Float16 h4 __attribute__((ext_vector_type(4)));   // 4 fp16 (8 B)
typedef __attribute__((ext_vector_type(4))) float facc4;   // 4 f32 acc

__device__ __forceinline__ void gload16(const void* g, void* l) {
  __builtin_amdgcn_global_load_lds((const __attribute__((address_space(1))) void*)g,
                                   (__attribute__((address_space(3))) void*)l, 16, 0, 0);
}

// ---------------- fp32 -> fp16 convert (plain; used for W1 and x) ----------------
__global__ void f2h_k(const float* __restrict__ in, unsigned short* __restrict__ out, int n4) {
  int i = blockIdx.x * 256 + threadIdx.x;
  int stride = gridDim.x * 256;
  for (; i < n4; i += stride) {
    float4 v = ((const float4*)in)[i];
    h4 o;
    o[0] = (_Float16)v.x; o[1] = (_Float16)v.y; o[2] = (_Float16)v.z; o[3] = (_Float16)v.w;
    ((h4*)out)[i] = o;
  }
}

// ---------------- LN-folded weight convert: wh[o,k]=W[o,k]*istd*lnw[k]; c[o]=sum_k W[o,k]*t[k] ----
__global__ __launch_bounds__(256) void w2h_fold_k(
    const float* __restrict__ W, const float* __restrict__ lnw, const float* __restrict__ lnb,
    const float* __restrict__ sums, float inv_count,
    unsigned short* __restrict__ wh, float* __restrict__ cvec, int K) {
  const int o = blockIdx.x, tid = threadIdx.x;
  float mu = sums[0] * inv_count;
  float var = sums[1] * inv_count - mu * mu;
  float istd = rsqrtf(var + 1e-5f);
  const float* wrow = W + (size_t)o * K;
  float dot = 0.f;
  for (int k4 = tid; k4 < (K >> 2); k4 += 256) {
    float4 wv = ((const float4*)wrow)[k4];
    float4 gw = ((const float4*)lnw)[k4];
    float4 gb = ((const float4*)lnb)[k4];
    float sx = istd * gw.x, sy = istd * gw.y, sz = istd * gw.z, sw = istd * gw.w;
    h4 oq;
    oq[0] = (_Float16)(wv.x * sx); oq[1] = (_Float16)(wv.y * sy);
    oq[2] = (_Float16)(wv.z * sz); oq[3] = (_Float16)(wv.w * sw);
    ((h4*)(wh + (size_t)o * K))[k4] = oq;
    dot += wv.x * (gb.x - mu * sx) + wv.y * (gb.y - mu * sy)
         + wv.z * (gb.z - mu * sz) + wv.w * (gb.w - mu * sw);
  }
#pragma unroll
  for (int m = 32; m; m >>= 1) dot += __shfl_down(dot, m);
  __shared__ float r[4];
  if ((tid & 63) == 0) r[tid >> 6] = dot;
  __syncthreads();
  if (tid == 0) cvec[o] = r[0] + r[1] + r[2] + r[3];
}

// ---------------- fp16 MFMA GEMM, 128x128 tile, BK=32, ring-3, 3 blocks/CU (replay-proven) ----
__global__ __launch_bounds__(256, 3) void gemm_f16(
    const unsigned short* __restrict__ A, const unsigned short* __restrict__ B,
    unsigned short* __restrict__ Hout,
    float* __restrict__ als, float* __restrict__ ald,
    const float* __restrict__ a_src, const float* __restrict__ a_dst,
    const float* __restrict__ cvec,
    int M, int Nn, int K, int C, int H, int gx, int nwg) {
  __shared__ __align__(16) unsigned short lds[3 * 8192];   // 48 KB
  const int tid = threadIdx.x, lane = tid & 63, wv = tid >> 6;

  int lin = blockIdx.x;
  int q = nwg >> 3, r = nwg & 7;
  int xcd = lin & 7, idx = lin >> 3;
  int swz = (xcd < r) ? (xcd * (q + 1) + idx) : (r * (q + 1) + (xcd - r) * q + idx);
  const int bx = swz % gx, by = swz / gx;
  const int brow = by * 128, bcol = bx * 128;
  const int wr = wv >> 1, wc = wv & 1;   // 2x2 wave grid, 64x64 out per wave

  const int l4 = lane >> 2;
  const int srcslot = ((lane & 3) ^ ((lane >> 3) & 3)) * 8;
  int ar0 = brow + wv * 32 + l4;        if (ar0 > M - 1)  ar0 = M - 1;
  int ar1 = brow + wv * 32 + 16 + l4;   if (ar1 > M - 1)  ar1 = M - 1;
  int br0 = bcol + wv * 32 + l4;        if (br0 > Nn - 1) br0 = Nn - 1;
  int br1 = bcol + wv * 32 + 16 + l4;   if (br1 > Nn - 1) br1 = Nn - 1;
  const unsigned short* pa0 = A + (size_t)ar0 * K + srcslot;
  const unsigned short* pa1 = A + (size_t)ar1 * K + srcslot;
  const unsigned short* pb0 = B + (size_t)br0 * K + srcslot;
  const unsigned short* pb1 = B + (size_t)br1 * K + srcslot;
  const int d0 = wv * 1024, d1 = wv * 1024 + 512;

  const int rsl = ((lane >> 4) ^ (((lane & 15) >> 1) & 3)) * 8;
  const int baseA = (wr * 64 + (lane & 15)) * 32 + rsl;
  const int baseB = 4096 + (wc * 64 + (lane & 15)) * 32 + rsl;

  facc4 acc[4][4] = {};
  const int nt = K >> 5;

  auto STAGE = [&](int kt, int buf) {
    unsigned short* Lq = &lds[buf * 8192];
    const int kb = kt * 32;
    gload16(pa0 + kb, Lq + d0);
    gload16(pa1 + kb, Lq + d1);
    gload16(pb0 + kb, Lq + 4096 + d0);
    gload16(pb1 + kb, Lq + 4096 + d1);
  };

  STAGE(0, 0);
  STAGE(1, 1);
  asm volatile("s_waitcnt vmcnt(4)" ::: "memory");
  __builtin_amdgcn_s_barrier();
  asm volatile("" ::: "memory");

  int cb = 0, sb = 2;
  for (int kt = 0; kt < nt; ++kt) {
    if (kt + 2 < nt) STAGE(kt + 2, sb);
    const unsigned short* Lq = &lds[cb * 8192];
    h8 af[4], bf[4];
#pragma unroll
    for (int m = 0; m < 4; ++m) af[m] = *(const h8*)(Lq + baseA + m * 512);
#pragma unroll
    for (int n = 0; n < 4; ++n) bf[n] = *(const h8*)(Lq + baseB + n * 512);
    __builtin_amdgcn_s_setprio(1);
#pragma unroll
    for (int m = 0; m < 4; ++m)
#pragma unroll
      for (int n = 0; n < 4; ++n)
        acc[m][n] = __builtin_amdgcn_mfma_f32_16x16x32_f16(af[m], bf[n], acc[m][n], 0, 0, 0);
    __builtin_amdgcn_s_setprio(0);
    if (kt + 2 < nt) asm volatile("s_waitcnt vmcnt(4)" ::: "memory");
    else             asm volatile("s_waitcnt vmcnt(0)" ::: "memory");
    __builtin_amdgcn_s_barrier();
    asm volatile("" ::: "memory");
    cb = (cb == 2) ? 0 : cb + 1;
    sb = (sb == 2) ? 0 : sb + 1;
  }

  const int rbase = brow + wr * 64 + ((lane >> 4) << 2);
  const int cbase = bcol + wc * 64 + (lane & 15);

#pragma unroll
  for (int n = 0; n < 4; ++n) {
    int col = cbase + n * 16;
    float cadd = (col < Nn) ? cvec[col] : 0.f;
#pragma unroll
    for (int m = 0; m < 4; ++m)
#pragma unroll
      for (int r2 = 0; r2 < 4; ++r2) acc[m][n][r2] += cadd;
  }

  float asv[4], adv[4];
#pragma unroll
  for (int n = 0; n < 4; ++n) {
    int col = cbase + n * 16;
    bool ok = col < Nn;
    asv[n] = ok ? a_src[col] : 0.f;
    adv[n] = ok ? a_dst[col] : 0.f;
  }
  const int hh = (bcol + wc * 64) / C;
#pragma unroll
  for (int m = 0; m < 4; ++m)
#pragma unroll
    for (int r2 = 0; r2 < 4; ++r2) {
      float s1 = 0.f, s2 = 0.f;
#pragma unroll
      for (int n = 0; n < 4; ++n) { float v = acc[m][n][r2]; s1 += v * asv[n]; s2 += v * adv[n]; }
#pragma unroll
      for (int mm = 1; mm < 16; mm <<= 1) { s1 += __shfl_xor(s1, mm); s2 += __shfl_xor(s2, mm); }
      int row = rbase + m * 16 + r2;
      if ((lane & 15) == 0 && row < M) {
        atomicAdd(&als[row * H + hh], s1);
        atomicAdd(&ald[row * H + hh], s2);
      }
    }

#pragma unroll
  for (int m = 0; m < 4; ++m)
#pragma unroll
    for (int n = 0; n < 4; ++n) {
      int col = cbase + n * 16;
      if (col >= Nn) continue;
#pragma unroll
      for (int r2 = 0; r2 < 4; ++r2) {
        int row = rbase + m * 16 + r2;
        if (row < M) {
          _Float16 hv = (_Float16)acc[m][n][r2];
          Hout[(size_t)row * Nn + col] = *(unsigned short*)&hv;
        }
      }
    }
}

// ---------------- L1 head-block GEMM: X[N,3584] per-head = aggx_h @ W1_h^T + bias ----
__global__ __launch_bounds__(256, 3) void gemm_f16_hd(
    const unsigned short* __restrict__ Aall, const unsigned short* __restrict__ Ball,
    unsigned short* __restrict__ Xout, const float* __restrict__ bias,
    float* __restrict__ lnsums, int M, int K, int Fo, int Ch, int gx, int nwg) {
  __shared__ __align__(16) unsigned short lds[3 * 8192];
  const int tid = threadIdx.x, lane = tid & 63, wv = tid >> 6;
  const int head = blockIdx.y;
  const unsigned short* A = Aall + (size_t)head * M * K;
  const unsigned short* B = Ball + (size_t)head * Ch * K;

  int lin = blockIdx.x;
  int q = nwg >> 3, r = nwg & 7;
  int xcd = lin & 7, idx = lin >> 3;
  int swz = (xcd < r) ? (xcd * (q + 1) + idx) : (r * (q + 1) + (xcd - r) * q + idx);
  const int bx = swz % gx, by = swz / gx;
  const int brow = by * 128, bcol = bx * 128;
  const int wr = wv >> 1, wc = wv & 1;

  const int l4 = lane >> 2;
  const int srcslot = ((lane & 3) ^ ((lane >> 3) & 3)) * 8;
  int ar0 = brow + wv * 32 + l4;        if (ar0 > M - 1)  ar0 = M - 1;
  int ar1 = brow + wv * 32 + 16 + l4;   if (ar1 > M - 1)  ar1 = M - 1;
  int br0 = bcol + wv * 32 + l4;        if (br0 > Ch - 1) br0 = Ch - 1;
  int br1 = bcol + wv * 32 + 16 + l4;   if (br1 > Ch - 1) br1 = Ch - 1;
  const unsigned short* pa0 = A + (size_t)ar0 * K + srcslot;
  const unsigned short* pa1 = A + (size_t)ar1 * K + srcslot;
  const unsigned short* pb0 = B + (size_t)br0 * K + srcslot;
  const unsigned short* pb1 = B + (size_t)br1 * K + srcslot;
  const int d0 = wv * 1024, d1 = wv * 1024 + 512;

  const int rsl = ((lane >> 4) ^ (((lane & 15) >> 1) & 3)) * 8;
  const int baseA = (wr * 64 + (lane & 15)) * 32 + rsl;
  const int baseB = 4096 + (wc * 64 + (lane & 15)) * 32 + rsl;

  facc4 acc[4][4] = {};
  const int nt = K >> 5;

  auto STAGE = [&](int kt, int buf) {
    unsigned short* Lq = &lds[buf * 8192];
    const int kb = kt * 32;
    gload16(pa0 + kb, Lq + d0);
    gload16(pa1 + kb, Lq + d1);
    gload16(pb0 + kb, Lq + 4096 + d0);
    gload16(pb1 + kb, Lq + 4096 + d1);
  };

  STAGE(0, 0);
  STAGE(1, 1);
  asm volatile("s_waitcnt vmcnt(4)" ::: "memory");
  __builtin_amdgcn_s_barrier();
  asm volatile("" ::: "memory");

  int cb = 0, sb = 2;
  for (int kt = 0; kt < nt; ++kt) {
    if (kt + 2 < nt) STAGE(kt + 2, sb);
    const unsigned short* Lq = &lds[cb * 8192];
    h8 af[4], bf[4];
#pragma unroll
    for (int m = 0; m < 4; ++m) af[m] = *(const h8*)(Lq + baseA + m * 512);
#pragma unroll
    for (int n = 0; n < 4; ++n) bf[n] = *(const h8*)(Lq + baseB + n * 512);
    __builtin_amdgcn_s_setprio(1);
#pragma unroll
    for (int m = 0; m < 4; ++m)
#pragma unroll
      for (int n = 0; n < 4; ++n)
        acc[m][n] = __builtin_amdgcn_mfma_f32_16x16x32_f16(af[m], bf[n], acc[m][n], 0, 0, 0);
    __builtin_amdgcn_s_setprio(0);
    if (kt + 2 < nt) asm volatile("s_waitcnt vmcnt(4)" ::: "memory");
    else             asm volatile("s_waitcnt vmcnt(0)" ::: "memory");
    __builtin_amdgcn_s_barrier();
    asm volatile("" ::: "memory");
    cb = (cb == 2) ? 0 : cb + 1;
    sb = (sb == 2) ? 0 : sb + 1;
  }

  const int rbase = brow + wr * 64 + ((lane >> 4) << 2);
  const int cbase = bcol + wc * 64 + (lane & 15);
  float s1 = 0.f, s2 = 0.f;
#pragma unroll
  for (int n = 0; n < 4; ++n) {
    int col_l = cbase + n * 16;
    if (col_l >= Ch) continue;
    int col_g = head * Ch + col_l;
    float bv = bias[col_g];
#pragma unroll
    for (int m = 0; m < 4; ++m)
#pragma unroll
      for (int r2 = 0; r2 < 4; ++r2) {
        int row = rbase + m * 16 + r2;
        if (row < M) {
          float v = acc[m][n][r2] + bv;
          float rv = v > 0.f ? v : 0.f;
          _Float16 hv = (_Float16)rv;
          Xout[(size_t)row * Fo + col_g] = *(unsigned short*)&hv;
          s1 += rv; s2 += rv * rv;
        }
      }
  }
#pragma unroll
  for (int m = 32; m; m >>= 1) { s1 += __shfl_down(s1, m); s2 += __shfl_down(s2, m); }
  __shared__ float r1s[4], r2s[4];
  if (lane == 0) { r1s[wv] = s1; r2s[wv] = s2; }
  __syncthreads();
  if (tid == 0) {
    atomicAdd(&lnsums[0], r1s[0] + r1s[1] + r1s[2] + r1s[3]);
    atomicAdd(&lnsums[1], r2s[0] + r2s[1] + r2s[2] + r2s[3]);
  }
}

// ---------------- L1 logit weights: w~[h,k] = sum_c a[h,c]·W[h*C+c,k] (fp32) ----------------
__global__ void attw_k(const float* __restrict__ W, const float* __restrict__ as_,
                       const float* __restrict__ ad_, float* __restrict__ ws,
                       float* __restrict__ wd, int C, int K) {
  int t = blockIdx.x * 256 + threadIdx.x;   // t < 8*K
  int h = t / K, k = t % K;
  float s1 = 0.f, s2 = 0.f;
  for (int c = 0; c < C; ++c) {
    float w = W[(size_t)(h * C + c) * K + k];
    s1 += as_[h * C + c] * w;
    s2 += ad_[h * C + c] * w;
  }
  ws[t] = s1; wd[t] = s2;
}

// ---------------- L1 logits in x-space ----------------
__global__ __launch_bounds__(256) void logits_x_k(
    const float* __restrict__ x, const float* __restrict__ ws, const float* __restrict__ wd,
    float* __restrict__ als, float* __restrict__ ald, int n) {
  __shared__ float sws[2048], swd[2048];
  for (int i = threadIdx.x; i < 2048; i += 256) { sws[i] = ws[i]; swd[i] = wd[i]; }
  __syncthreads();
  int node = blockIdx.x * 4 + (threadIdx.x >> 6);
  int lane = threadIdx.x & 63;
  if (node >= n) return;
  const float* xp = x + (size_t)node * 256;
  float s1[8] = {}, s2[8] = {};
  for (int k = lane; k < 256; k += 64) {
    float xv = xp[k];
#pragma unroll
    for (int h = 0; h < 8; ++h) { s1[h] += xv * sws[h * 256 + k]; s2[h] += xv * swd[h * 256 + k]; }
  }
#pragma unroll
  for (int m = 32; m; m >>= 1)
#pragma unroll
    for (int h = 0; h < 8; ++h) { s1[h] += __shfl_down(s1[h], m); s2[h] += __shfl_down(s2[h], m); }
  if (lane == 0) {
#pragma unroll
    for (int h = 0; h < 8; ++h) { als[node * 8 + h] = s1[h]; ald[node * 8 + h] = s2[h]; }
  }
}

// ---------------- L1 x-space aggregation (alpha pre-normalized in s_al) ----------------
__global__ __launch_bounds__(256) void aggregate_x_k(
    const unsigned short* __restrict__ x16,
    const float* __restrict__ als, const float* __restrict__ ald,
    const int* __restrict__ rowptr, const int* __restrict__ esrc,
    unsigned short* __restrict__ aggx, int n) {
  const int node = blockIdx.x, tid = threadIdx.x;
  int beg = rowptr[node];
  int deg = rowptr[node + 1] - beg;
  if (deg > 64) deg = 64;
  __shared__ int   s_src[64];
  __shared__ float s_al[64][8];
  __shared__ unsigned short s_x[64][256];   // 32 KB
  float aldv[8];
#pragma unroll
  for (int h = 0; h < 8; ++h) aldv[h] = ald[node * 8 + h];
  for (int d = tid; d < deg; d += 256) {
    int s = esrc[beg + d];
    s_src[d] = s;
#pragma unroll
    for (int h = 0; h < 8; ++h) {
      float v = als[s * 8 + h] + aldv[h];
      s_al[d][h] = (v >= 0.f) ? v : 0.2f * v;
    }
  }
  __syncthreads();
  if (tid < 8) {
    float m = -1e30f;
    for (int d = 0; d < deg; ++d) m = fmaxf(m, s_al[d][tid]);
    float s = 0.f;
    for (int d = 0; d < deg; ++d) { float p = __expf(s_al[d][tid] - m); s_al[d][tid] = p; s += p; }
    float inv = 1.f / (s + 1e-16f);
    for (int d = 0; d < deg; ++d) s_al[d][tid] *= inv;
  }
  for (int c = tid; c < deg * 32; c += 256) {
    int d = c >> 5, q2 = c & 31;
    ((h8*)s_x[d])[q2] = ((const h8*)(x16 + (size_t)s_src[d] * 256))[q2];
  }
  __syncthreads();
  const int h = tid >> 5, k8 = tid & 31;
  float a[8] = {};
  for (int d = 0; d < deg; ++d) {
    float al = s_al[d][h];
    h8 xv = ((const h8*)s_x[d])[k8];
#pragma unroll
    for (int j = 0; j < 8; ++j) a[j] = fmaf(al, (float)xv[j], a[j]);
  }
  h8 o;
#pragma unroll
  for (int j = 0; j < 8; ++j) o[j] = (_Float16)a[j];
  *(h8*)(aggx + ((size_t)h * n + node) * 256 + k8 * 8) = o;
}

// ---------------- CSR build ----------------
__global__ void count_deg_k(const int* __restrict__ ei, int* __restrict__ deg, int Ereal, int Etot) {
  int e = blockIdx.x * 256 + threadIdx.x;
  if (e >= Etot) return;
  int dst = (e < Ereal) ? ei[Ereal + e] : (e - Ereal);
  atomicAdd(&deg[dst], 1);
}

__global__ void scan_k(const int* __restrict__ deg, int* __restrict__ rowptr, int n) {
  __shared__ int sums[1024];
  int t = threadIdx.x;
  int base = t * 10;
  int loc[10]; int s = 0;
#pragma unroll
  for (int i = 0; i < 10; ++i) { int idx = base + i; int d = (idx < n) ? deg[idx] : 0; loc[i] = s; s += d; }
  sums[t] = s;
  __syncthreads();
  for (int off = 1; off < 1024; off <<= 1) {
    int add = (t >= off) ? sums[t - off] : 0;
    __syncthreads();
    sums[t] += add;
    __syncthreads();
  }
  int excl = sums[t] - s;
#pragma unroll
  for (int i = 0; i < 10; ++i) { int idx = base + i; if (idx < n) rowptr[idx] = excl + loc[i]; }
  if (t == 1023) rowptr[n] = sums[1023];
}

__global__ void scatter_k(const int* __restrict__ ei, const int* __restrict__ rowptr,
                          int* __restrict__ fill, int* __restrict__ esrc,
                          int Ereal, int Etot) {
  int e = blockIdx.x * 256 + threadIdx.x;
  if (e >= Etot) return;
  int src = (e < Ereal) ? ei[e] : (e - Ereal);
  int dst = (e < Ereal) ? ei[Ereal + e] : (e - Ereal);
  int pos = rowptr[dst] + atomicAdd(&fill[dst], 1);
  esrc[pos] = src;
}

// ---------------- aggregation + fused edge-softmax (CSR, no atomics) ----------------
// Round-12 config (BS=256 everywhere, 8 blocks/CU for latency hiding); alpha pre-normalized.
template <int H, bool FP32OUT, bool STATS>
__global__ __launch_bounds__(256) void aggregate_k(
    const unsigned short* __restrict__ hfp,
    const float* __restrict__ als, const float* __restrict__ ald,
    const int* __restrict__ rowptr, const int* __restrict__ esrc,
    const float* __restrict__ bias, void* __restrict__ outv,
    float* __restrict__ lnsums, int C, int F) {
  const int node = blockIdx.x;
  const int tid = threadIdx.x;
  int beg = rowptr[node];
  int deg = rowptr[node + 1] - beg;
  if (deg > 128) deg = 128;
  __shared__ int   s_src[128];
  __shared__ float s_p[128][H];
  float aldv[H];
#pragma unroll
  for (int h = 0; h < H; ++h) aldv[h] = ald[node * H + h];
  for (int d = tid; d < deg; d += 256) {
    int s = esrc[beg + d];
    s_src[d] = s;
#pragma unroll
    for (int h = 0; h < H; ++h) {
      float v = als[s * H + h] + aldv[h];
      s_p[d][h] = (v >= 0.f) ? v : 0.2f * v;
    }
  }
  __syncthreads();
  if (tid < H) {
    float m = -1e30f;
    for (int d = 0; d < deg; ++d) m = fmaxf(m, s_p[d][tid]);
    float s = 0.f;
    for (int d = 0; d < deg; ++d) { float p = __expf(s_p[d][tid] - m); s_p[d][tid] = p; s += p; }
    float inv = 1.f / (s + 1e-16f);
    for (int d = 0; d < deg; ++d) s_p[d][tid] *= inv;
  }
  __syncthreads();

  float s1 = 0.f, s2 = 0.f;
  const int F8 = F >> 3;
  for (int c8 = tid; c8 < F8; c8 += 256) {
    int f0 = c8 * 8;
    int h = f0 / C;
    float a[8];
    float4 b0 = *(const float4*)(bias + f0);
    float4 b1 = *(const float4*)(bias + f0 + 4);
    a[0] = b0.x; a[1] = b0.y; a[2] = b0.z; a[3] = b0.w;
    a[4] = b1.x; a[5] = b1.y; a[6] = b1.z; a[7] = b1.w;
    for (int d = 0; d < deg; ++d) {
      float al = s_p[d][h];
      h8 hv = *(const h8*)(hfp + (size_t)s_src[d] * F + f0);
#pragma unroll
      for (int j = 0; j < 8; ++j) a[j] = fmaf(al, (float)hv[j], a[j]);
    }
    if (STATS) {
#pragma unroll
      for (int j = 0; j < 8; ++j) { float v = a[j] > 0.f ? a[j] : 0.f; a[j] = v; s1 += v; s2 += v * v; }
    }
    size_t i = (size_t)node * F + f0;
    if (FP32OUT) {
      float4 o0 = {a[0], a[1], a[2], a[3]};
      float4 o1 = {a[4], a[5], a[6], a[7]};
      *(float4*)((float*)outv + i) = o0;
      *(float4*)((float*)outv + i + 4) = o1;
    } else {
      h8 o;
#pragma unroll
      for (int j = 0; j < 8; ++j) o[j] = (_Float16)a[j];
      *(h8*)((unsigned short*)outv + i) = o;
    }
  }
  if (STATS) {
#pragma unroll
    for (int m = 32; m; m >>= 1) { s1 += __shfl_down(s1, m); s2 += __shfl_down(s2, m); }
    __shared__ float r1[4], r2[4];
    if ((tid & 63) == 0) { r1[tid >> 6] = s1; r2[tid >> 6] = s2; }
    __syncthreads();
    if (tid == 0) {
      atomicAdd(&lnsums[0], r1[0] + r1[1] + r1[2] + r1[3]);
      atomicAdd(&lnsums[1], r2[0] + r2[1] + r2[2] + r2[3]);
    }
  }
}

// ---------------- host orchestration ----------------
extern "C" void kernel_launch(void* const* d_in, const int* in_sizes, int n_in,
                              void* d_out, int out_size, void* d_ws, size_t ws_size,
                              hipStream_t stream) {
  const int N = 10000, Ereal = 50000, Etot = 60000;
  const float* x  = (const float*)d_in[0];
  const int*   ei = (const int*)d_in[1];
  const float* W[4]    = {(const float*)d_in[2],  (const float*)d_in[8],  (const float*)d_in[14], (const float*)d_in[20]};
  const float* asrc[4] = {(const float*)d_in[3],  (const float*)d_in[9],  (const float*)d_in[15], (const float*)d_in[21]};
  const float* adst[4] = {(const float*)d_in[4],  (const float*)d_in[10], (const float*)d_in[16], (const float*)d_in[22]};
  const float* bias[4] = {(const float*)d_in[5],  (const float*)d_in[11], (const float*)d_in[17], (const float*)d_in[23]};
  const float* lnw[3]  = {(const float*)d_in[6],  (const float*)d_in[12], (const float*)d_in[18]};
  const float* lnb[3]  = {(const float*)d_in[7],  (const float*)d_in[13], (const float*)d_in[19]};

  const int fin[4]  = {256, 3584, 3072, 2048};
  const int fout[4] = {3584, 3072, 2048, 1000};
  const int CH[4]   = {448, 384, 256, 1000};

  // workspace carve-up (~170 MB total)
  size_t off = 0;
  char* base = (char*)d_ws;
  auto alloc = [&](size_t bytes) -> void* {
    void* p = base + off;
    off += (bytes + 255) & ~(size_t)255;
    return p;
  };
  unsigned short* xh  = (unsigned short*)alloc((size_t)N * 3584 * 2);
  unsigned short* hh  = (unsigned short*)alloc((size_t)N * 3584 * 2);   // aliases aggx in L1
  unsigned short* wh  = (unsigned short*)alloc((size_t)3072 * 3584 * 2);
  float*          alsA   = (float*)alloc((size_t)4 * N * 8 * 4);        // contiguous: alsA|aldA|lnsA (one memset)
  float*          aldA   = (float*)alloc((size_t)4 * N * 8 * 4);
  float*          lnsA   = (float*)alloc(256);                          // 4 slots x 2 floats
  int*            deg    = (int*)alloc((size_t)N * 4);
  int*            fill   = (int*)alloc((size_t)N * 4);
  int*            rowptr = (int*)alloc((size_t)(N + 1) * 4);
  int*            esrc   = (int*)alloc((size_t)Etot * 4);
  float*          wsrc   = (float*)alloc((size_t)8 * 256 * 4);
  float*          wdst   = (float*)alloc((size_t)8 * 256 * 4);
  float*          cvec   = (float*)alloc((size_t)3072 * 4);

  auto cdiv = [](int a, int b) { return (a + b - 1) / b; };

  // --- CSR build + one-shot zero of logit accumulators and LN-stat slots ---
  hipMemsetAsync(deg, 0, (size_t)N * 4, stream);
  hipMemsetAsync(fill, 0, (size_t)N * 4, stream);
  hipMemsetAsync(alsA, 0, (size_t)4 * N * 8 * 4 * 2 + 256, stream);
  count_deg_k<<<cdiv(Etot, 256), 256, 0, stream>>>(ei, deg, Ereal, Etot);
  scan_k<<<1, 1024, 0, stream>>>(deg, rowptr, N);
  scatter_k<<<cdiv(Etot, 256), 256, 0, stream>>>(ei, rowptr, fill, esrc, Ereal, Etot);

  // --- input features -> fp16 ---
  {
    int n4 = (N * fin[0]) / 4;
    f2h_k<<<min(2048, cdiv(n4, 256)), 256, 0, stream>>>(x, xh, n4);
  }

  // ================= layer 1 (x-space aggregation: K=256 << Fo=3584) =================
  {
    float* als = alsA;
    float* ald = aldA;
    attw_k<<<8, 256, 0, stream>>>(W[0], asrc[0], adst[0], wsrc, wdst, 448, 256);
    logits_x_k<<<cdiv(N, 4), 256, 0, stream>>>(x, wsrc, wdst, als, ald, N);
    {
      int n4 = (3584 * 256) / 4;
      f2h_k<<<min(2048, cdiv(n4, 256)), 256, 0, stream>>>(W[0], wh, n4);
    }
    aggregate_x_k<<<N, 256, 0, stream>>>(xh, als, ald, rowptr, esrc, hh, N);
    // per-head GEMM: xh = relu(aggx @ W1^T + b1), LN1 stats -> slot 0
    {
      int gx = cdiv(448, 128), gy = cdiv(N, 128);
      int nwg = gx * gy;
      gemm_f16_hd<<<dim3(nwg, 8), 256, 0, stream>>>(hh, wh, xh, bias[0], lnsA,
                                                    N, 256, 3584, 448, gx, nwg);
    }
  }

  // ================= layers 2-4 (h-space aggregation, folded-LN weights) =================
  for (int l = 1; l < 4; ++l) {
    const int K = fin[l], Fo = fout[l], C = CH[l];
    const int H = (l == 3) ? 1 : 8;
    float* als = alsA + (size_t)l * N * 8;
    float* ald = aldA + (size_t)l * N * 8;

    // LN-folded weights: wh = W*istd*lnw, cvec[o] = sum_f t[f]*W[o,f]
    w2h_fold_k<<<Fo, 256, 0, stream>>>(W[l], lnw[l - 1], lnb[l - 1], lnsA + (l - 1) * 2,
                                       1.0f / (float)(N * fin[l]), wh, cvec, K);

    // GEMM + c add + fused logits: hh[N,Fo] = xh @ wh^T + c
    {
      int gx = cdiv(Fo, 128), gy = cdiv(N, 128);
      int nwg = gx * gy;
      gemm_f16<<<nwg, 256, 0, stream>>>(xh, wh, hh, als, ald, asrc[l], adst[l], cvec,
                                        N, Fo, K, C, H, gx, nwg);
    }

    // aggregate + fused softmax (+ relu + LN stats for layers 2-3)
    if (l < 3) {
      aggregate_k<8, false, true><<<N, 256, 0, stream>>>(hh, als, ald, rowptr, esrc,
                                                         bias[l], xh, lnsA + l * 2, C, Fo);
    } else {
      aggregate_k<1, true, false><<<N, 256, 0, stream>>>(hh, als, ald, rowptr, esrc,
                                                         bias[l], d_out, nullptr, C, Fo);
    }
  }
}

// Round 15
// 1403.554 us; speedup vs baseline: 1.0406x; 1.0406x over previous
//
#include <hip/hip_runtime.h>

// ---------------- common types/helpers ----------------
typedef _Float16 h8 __attribute__((ext_vector_type(8)));   // 8 fp16 (16 B)
typedef _Float16 h4 __attribute__((ext_vector_type(4)));   // 4 fp16 (8 B)
typedef __attribute__((ext_vector_type(4))) float facc4;   // 4 f32 acc

__device__ __forceinline__ void gload16(const void* g, void* l) {
  __builtin_amdgcn_global_load_lds((const __attribute__((address_space(1))) void*)g,
                                   (__attribute__((address_space(3))) void*)l, 16, 0, 0);
}

// ---------------- fp32 -> fp16 convert (plain; used for W1 and x) ----------------
__global__ void f2h_k(const float* __restrict__ in, unsigned short* __restrict__ out, int n4) {
  int i = blockIdx.x * 256 + threadIdx.x;
  int stride = gridDim.x * 256;
  for (; i < n4; i += stride) {
    float4 v = ((const float4*)in)[i];
    h4 o;
    o[0] = (_Float16)v.x; o[1] = (_Float16)v.y; o[2] = (_Float16)v.z; o[3] = (_Float16)v.w;
    ((h4*)out)[i] = o;
  }
}

// ---------------- LN-folded weight convert: wh[o,k]=W[o,k]*istd*lnw[k]; c[o]=sum_k W[o,k]*t[k] ----
__global__ __launch_bounds__(256) void w2h_fold_k(
    const float* __restrict__ W, const float* __restrict__ lnw, const float* __restrict__ lnb,
    const float* __restrict__ sums, float inv_count,
    unsigned short* __restrict__ wh, float* __restrict__ cvec, int K) {
  const int o = blockIdx.x, tid = threadIdx.x;
  float mu = sums[0] * inv_count;
  float var = sums[1] * inv_count - mu * mu;
  float istd = rsqrtf(var + 1e-5f);
  const float* wrow = W + (size_t)o * K;
  float dot = 0.f;
  for (int k4 = tid; k4 < (K >> 2); k4 += 256) {
    float4 wv = ((const float4*)wrow)[k4];
    float4 gw = ((const float4*)lnw)[k4];
    float4 gb = ((const float4*)lnb)[k4];
    float sx = istd * gw.x, sy = istd * gw.y, sz = istd * gw.z, sw = istd * gw.w;
    h4 oq;
    oq[0] = (_Float16)(wv.x * sx); oq[1] = (_Float16)(wv.y * sy);
    oq[2] = (_Float16)(wv.z * sz); oq[3] = (_Float16)(wv.w * sw);
    ((h4*)(wh + (size_t)o * K))[k4] = oq;
    dot += wv.x * (gb.x - mu * sx) + wv.y * (gb.y - mu * sy)
         + wv.z * (gb.z - mu * sz) + wv.w * (gb.w - mu * sw);
  }
#pragma unroll
  for (int m = 32; m; m >>= 1) dot += __shfl_down(dot, m);
  __shared__ float r[4];
  if ((tid & 63) == 0) r[tid >> 6] = dot;
  __syncthreads();
  if (tid == 0) cvec[o] = r[0] + r[1] + r[2] + r[3];
}

// ---------------- fp16 MFMA GEMM, 128x128 tile, BK=32, ring-3, 3 blocks/CU (replay-proven) ----
__global__ __launch_bounds__(256, 3) void gemm_f16(
    const unsigned short* __restrict__ A, const unsigned short* __restrict__ B,
    unsigned short* __restrict__ Hout,
    float* __restrict__ als, float* __restrict__ ald,
    const float* __restrict__ a_src, const float* __restrict__ a_dst,
    const float* __restrict__ cvec,
    int M, int Nn, int K, int C, int H, int gx, int nwg) {
  __shared__ __align__(16) unsigned short lds[3 * 8192];   // 48 KB
  const int tid = threadIdx.x, lane = tid & 63, wv = tid >> 6;

  int lin = blockIdx.x;
  int q = nwg >> 3, r = nwg & 7;
  int xcd = lin & 7, idx = lin >> 3;
  int swz = (xcd < r) ? (xcd * (q + 1) + idx) : (r * (q + 1) + (xcd - r) * q + idx);
  const int bx = swz % gx, by = swz / gx;
  const int brow = by * 128, bcol = bx * 128;
  const int wr = wv >> 1, wc = wv & 1;   // 2x2 wave grid, 64x64 out per wave

  const int l4 = lane >> 2;
  const int srcslot = ((lane & 3) ^ ((lane >> 3) & 3)) * 8;
  int ar0 = brow + wv * 32 + l4;        if (ar0 > M - 1)  ar0 = M - 1;
  int ar1 = brow + wv * 32 + 16 + l4;   if (ar1 > M - 1)  ar1 = M - 1;
  int br0 = bcol + wv * 32 + l4;        if (br0 > Nn - 1) br0 = Nn - 1;
  int br1 = bcol + wv * 32 + 16 + l4;   if (br1 > Nn - 1) br1 = Nn - 1;
  const unsigned short* pa0 = A + (size_t)ar0 * K + srcslot;
  const unsigned short* pa1 = A + (size_t)ar1 * K + srcslot;
  const unsigned short* pb0 = B + (size_t)br0 * K + srcslot;
  const unsigned short* pb1 = B + (size_t)br1 * K + srcslot;
  const int d0 = wv * 1024, d1 = wv * 1024 + 512;

  const int rsl = ((lane >> 4) ^ (((lane & 15) >> 1) & 3)) * 8;
  const int baseA = (wr * 64 + (lane & 15)) * 32 + rsl;
  const int baseB = 4096 + (wc * 64 + (lane & 15)) * 32 + rsl;

  facc4 acc[4][4] = {};
  const int nt = K >> 5;

  auto STAGE = [&](int kt, int buf) {
    unsigned short* Lq = &lds[buf * 8192];
    const int kb = kt * 32;
    gload16(pa0 + kb, Lq + d0);
    gload16(pa1 + kb, Lq + d1);
    gload16(pb0 + kb, Lq + 4096 + d0);
    gload16(pb1 + kb, Lq + 4096 + d1);
  };

  STAGE(0, 0);
  STAGE(1, 1);
  asm volatile("s_waitcnt vmcnt(4)" ::: "memory");
  __builtin_amdgcn_s_barrier();
  asm volatile("" ::: "memory");

  int cb = 0, sb = 2;
  for (int kt = 0; kt < nt; ++kt) {
    if (kt + 2 < nt) STAGE(kt + 2, sb);
    const unsigned short* Lq = &lds[cb * 8192];
    h8 af[4], bf[4];
#pragma unroll
    for (int m = 0; m < 4; ++m) af[m] = *(const h8*)(Lq + baseA + m * 512);
#pragma unroll
    for (int n = 0; n < 4; ++n) bf[n] = *(const h8*)(Lq + baseB + n * 512);
    __builtin_amdgcn_s_setprio(1);
#pragma unroll
    for (int m = 0; m < 4; ++m)
#pragma unroll
      for (int n = 0; n < 4; ++n)
        acc[m][n] = __builtin_amdgcn_mfma_f32_16x16x32_f16(af[m], bf[n], acc[m][n], 0, 0, 0);
    __builtin_amdgcn_s_setprio(0);
    if (kt + 2 < nt) asm volatile("s_waitcnt vmcnt(4)" ::: "memory");
    else             asm volatile("s_waitcnt vmcnt(0)" ::: "memory");
    __builtin_amdgcn_s_barrier();
    asm volatile("" ::: "memory");
    cb = (cb == 2) ? 0 : cb + 1;
    sb = (sb == 2) ? 0 : sb + 1;
  }

  const int rbase = brow + wr * 64 + ((lane >> 4) << 2);
  const int cbase = bcol + wc * 64 + (lane & 15);

#pragma unroll
  for (int n = 0; n < 4; ++n) {
    int col = cbase + n * 16;
    float cadd = (col < Nn) ? cvec[col] : 0.f;
#pragma unroll
    for (int m = 0; m < 4; ++m)
#pragma unroll
      for (int r2 = 0; r2 < 4; ++r2) acc[m][n][r2] += cadd;
  }

  float asv[4], adv[4];
#pragma unroll
  for (int n = 0; n < 4; ++n) {
    int col = cbase + n * 16;
    bool ok = col < Nn;
    asv[n] = ok ? a_src[col] : 0.f;
    adv[n] = ok ? a_dst[col] : 0.f;
  }
  const int hh = (bcol + wc * 64) / C;
#pragma unroll
  for (int m = 0; m < 4; ++m)
#pragma unroll
    for (int r2 = 0; r2 < 4; ++r2) {
      float s1 = 0.f, s2 = 0.f;
#pragma unroll
      for (int n = 0; n < 4; ++n) { float v = acc[m][n][r2]; s1 += v * asv[n]; s2 += v * adv[n]; }
#pragma unroll
      for (int mm = 1; mm < 16; mm <<= 1) { s1 += __shfl_xor(s1, mm); s2 += __shfl_xor(s2, mm); }
      int row = rbase + m * 16 + r2;
      if ((lane & 15) == 0 && row < M) {
        atomicAdd(&als[row * H + hh], s1);
        atomicAdd(&ald[row * H + hh], s2);
      }
    }

#pragma unroll
  for (int m = 0; m < 4; ++m)
#pragma unroll
    for (int n = 0; n < 4; ++n) {
      int col = cbase + n * 16;
      if (col >= Nn) continue;
#pragma unroll
      for (int r2 = 0; r2 < 4; ++r2) {
        int row = rbase + m * 16 + r2;
        if (row < M) {
          _Float16 hv = (_Float16)acc[m][n][r2];
          Hout[(size_t)row * Nn + col] = *(unsigned short*)&hv;
        }
      }
    }
}

// ---------------- L1 head-block GEMM: X[N,3584] per-head = aggx_h @ W1_h^T + bias ----
__global__ __launch_bounds__(256, 3) void gemm_f16_hd(
    const unsigned short* __restrict__ Aall, const unsigned short* __restrict__ Ball,
    unsigned short* __restrict__ Xout, const float* __restrict__ bias,
    float* __restrict__ lnsums, int M, int K, int Fo, int Ch, int gx, int nwg) {
  __shared__ __align__(16) unsigned short lds[3 * 8192];
  const int tid = threadIdx.x, lane = tid & 63, wv = tid >> 6;
  const int head = blockIdx.y;
  const unsigned short* A = Aall + (size_t)head * M * K;
  const unsigned short* B = Ball + (size_t)head * Ch * K;

  int lin = blockIdx.x;
  int q = nwg >> 3, r = nwg & 7;
  int xcd = lin & 7, idx = lin >> 3;
  int swz = (xcd < r) ? (xcd * (q + 1) + idx) : (r * (q + 1) + (xcd - r) * q + idx);
  const int bx = swz % gx, by = swz / gx;
  const int brow = by * 128, bcol = bx * 128;
  const int wr = wv >> 1, wc = wv & 1;

  const int l4 = lane >> 2;
  const int srcslot = ((lane & 3) ^ ((lane >> 3) & 3)) * 8;
  int ar0 = brow + wv * 32 + l4;        if (ar0 > M - 1)  ar0 = M - 1;
  int ar1 = brow + wv * 32 + 16 + l4;   if (ar1 > M - 1)  ar1 = M - 1;
  int br0 = bcol + wv * 32 + l4;        if (br0 > Ch - 1) br0 = Ch - 1;
  int br1 = bcol + wv * 32 + 16 + l4;   if (br1 > Ch - 1) br1 = Ch - 1;
  const unsigned short* pa0 = A + (size_t)ar0 * K + srcslot;
  const unsigned short* pa1 = A + (size_t)ar1 * K + srcslot;
  const unsigned short* pb0 = B + (size_t)br0 * K + srcslot;
  const unsigned short* pb1 = B + (size_t)br1 * K + srcslot;
  const int d0 = wv * 1024, d1 = wv * 1024 + 512;

  const int rsl = ((lane >> 4) ^ (((lane & 15) >> 1) & 3)) * 8;
  const int baseA = (wr * 64 + (lane & 15)) * 32 + rsl;
  const int baseB = 4096 + (wc * 64 + (lane & 15)) * 32 + rsl;

  facc4 acc[4][4] = {};
  const int nt = K >> 5;

  auto STAGE = [&](int kt, int buf) {
    unsigned short* Lq = &lds[buf * 8192];
    const int kb = kt * 32;
    gload16(pa0 + kb, Lq + d0);
    gload16(pa1 + kb, Lq + d1);
    gload16(pb0 + kb, Lq + 4096 + d0);
    gload16(pb1 + kb, Lq + 4096 + d1);
  };

  STAGE(0, 0);
  STAGE(1, 1);
  asm volatile("s_waitcnt vmcnt(4)" ::: "memory");
  __builtin_amdgcn_s_barrier();
  asm volatile("" ::: "memory");

  int cb = 0, sb = 2;
  for (int kt = 0; kt < nt; ++kt) {
    if (kt + 2 < nt) STAGE(kt + 2, sb);
    const unsigned short* Lq = &lds[cb * 8192];
    h8 af[4], bf[4];
#pragma unroll
    for (int m = 0; m < 4; ++m) af[m] = *(const h8*)(Lq + baseA + m * 512);
#pragma unroll
    for (int n = 0; n < 4; ++n) bf[n] = *(const h8*)(Lq + baseB + n * 512);
    __builtin_amdgcn_s_setprio(1);
#pragma unroll
    for (int m = 0; m < 4; ++m)
#pragma unroll
      for (int n = 0; n < 4; ++n)
        acc[m][n] = __builtin_amdgcn_mfma_f32_16x16x32_f16(af[m], bf[n], acc[m][n], 0, 0, 0);
    __builtin_amdgcn_s_setprio(0);
    if (kt + 2 < nt) asm volatile("s_waitcnt vmcnt(4)" ::: "memory");
    else             asm volatile("s_waitcnt vmcnt(0)" ::: "memory");
    __builtin_amdgcn_s_barrier();
    asm volatile("" ::: "memory");
    cb = (cb == 2) ? 0 : cb + 1;
    sb = (sb == 2) ? 0 : sb + 1;
  }

  const int rbase = brow + wr * 64 + ((lane >> 4) << 2);
  const int cbase = bcol + wc * 64 + (lane & 15);
  float s1 = 0.f, s2 = 0.f;
#pragma unroll
  for (int n = 0; n < 4; ++n) {
    int col_l = cbase + n * 16;
    if (col_l >= Ch) continue;
    int col_g = head * Ch + col_l;
    float bv = bias[col_g];
#pragma unroll
    for (int m = 0; m < 4; ++m)
#pragma unroll
      for (int r2 = 0; r2 < 4; ++r2) {
        int row = rbase + m * 16 + r2;
        if (row < M) {
          float v = acc[m][n][r2] + bv;
          float rv = v > 0.f ? v : 0.f;
          _Float16 hv = (_Float16)rv;
          Xout[(size_t)row * Fo + col_g] = *(unsigned short*)&hv;
          s1 += rv; s2 += rv * rv;
        }
      }
  }
#pragma unroll
  for (int m = 32; m; m >>= 1) { s1 += __shfl_down(s1, m); s2 += __shfl_down(s2, m); }
  __shared__ float r1s[4], r2s[4];
  if (lane == 0) { r1s[wv] = s1; r2s[wv] = s2; }
  __syncthreads();
  if (tid == 0) {
    atomicAdd(&lnsums[0], r1s[0] + r1s[1] + r1s[2] + r1s[3]);
    atomicAdd(&lnsums[1], r2s[0] + r2s[1] + r2s[2] + r2s[3]);
  }
}

// ---------------- L1 logit weights: w~[h,k] = sum_c a[h,c]·W[h*C+c,k] (fp32) ----------------
__global__ void attw_k(const float* __restrict__ W, const float* __restrict__ as_,
                       const float* __restrict__ ad_, float* __restrict__ ws,
                       float* __restrict__ wd, int C, int K) {
  int t = blockIdx.x * 256 + threadIdx.x;   // t < 8*K
  int h = t / K, k = t % K;
  float s1 = 0.f, s2 = 0.f;
  for (int c = 0; c < C; ++c) {
    float w = W[(size_t)(h * C + c) * K + k];
    s1 += as_[h * C + c] * w;
    s2 += ad_[h * C + c] * w;
  }
  ws[t] = s1; wd[t] = s2;
}

// ---------------- L1 logits in x-space ----------------
__global__ __launch_bounds__(256) void logits_x_k(
    const float* __restrict__ x, const float* __restrict__ ws, const float* __restrict__ wd,
    float* __restrict__ als, float* __restrict__ ald, int n) {
  __shared__ float sws[2048], swd[2048];
  for (int i = threadIdx.x; i < 2048; i += 256) { sws[i] = ws[i]; swd[i] = wd[i]; }
  __syncthreads();
  int node = blockIdx.x * 4 + (threadIdx.x >> 6);
  int lane = threadIdx.x & 63;
  if (node >= n) return;
  const float* xp = x + (size_t)node * 256;
  float s1[8] = {}, s2[8] = {};
  for (int k = lane; k < 256; k += 64) {
    float xv = xp[k];
#pragma unroll
    for (int h = 0; h < 8; ++h) { s1[h] += xv * sws[h * 256 + k]; s2[h] += xv * swd[h * 256 + k]; }
  }
#pragma unroll
  for (int m = 32; m; m >>= 1)
#pragma unroll
    for (int h = 0; h < 8; ++h) { s1[h] += __shfl_down(s1[h], m); s2[h] += __shfl_down(s2[h], m); }
  if (lane == 0) {
#pragma unroll
    for (int h = 0; h < 8; ++h) { als[node * 8 + h] = s1[h]; ald[node * 8 + h] = s2[h]; }
  }
}

// ---------------- L1 x-space aggregation ----------------
__global__ __launch_bounds__(256) void aggregate_x_k(
    const unsigned short* __restrict__ x16,
    const float* __restrict__ als, const float* __restrict__ ald,
    const int* __restrict__ rowptr, const int* __restrict__ esrc,
    unsigned short* __restrict__ aggx, int n) {
  const int node = blockIdx.x, tid = threadIdx.x;
  int beg = rowptr[node];
  int deg = rowptr[node + 1] - beg;
  if (deg > 64) deg = 64;
  __shared__ int   s_src[64];
  __shared__ float s_al[64][8];
  __shared__ float s_inv[8];
  __shared__ unsigned short s_x[64][256];   // 32 KB
  float aldv[8];
#pragma unroll
  for (int h = 0; h < 8; ++h) aldv[h] = ald[node * 8 + h];
  for (int d = tid; d < deg; d += 256) {
    int s = esrc[beg + d];
    s_src[d] = s;
#pragma unroll
    for (int h = 0; h < 8; ++h) {
      float v = als[s * 8 + h] + aldv[h];
      s_al[d][h] = (v >= 0.f) ? v : 0.2f * v;
    }
  }
  __syncthreads();
  if (tid < 8) {
    float m = -1e30f;
    for (int d = 0; d < deg; ++d) m = fmaxf(m, s_al[d][tid]);
    float s = 0.f;
    for (int d = 0; d < deg; ++d) { float p = __expf(s_al[d][tid] - m); s_al[d][tid] = p; s += p; }
    s_inv[tid] = 1.f / (s + 1e-16f);
  }
  for (int c = tid; c < deg * 32; c += 256) {
    int d = c >> 5, q2 = c & 31;
    ((h8*)s_x[d])[q2] = ((const h8*)(x16 + (size_t)s_src[d] * 256))[q2];
  }
  __syncthreads();
  const int h = tid >> 5, k8 = tid & 31;
  float a[8] = {};
  for (int d = 0; d < deg; ++d) {
    float al = s_al[d][h] * s_inv[h];
    h8 xv = ((const h8*)s_x[d])[k8];
#pragma unroll
    for (int j = 0; j < 8; ++j) a[j] = fmaf(al, (float)xv[j], a[j]);
  }
  h8 o;
#pragma unroll
  for (int j = 0; j < 8; ++j) o[j] = (_Float16)a[j];
  *(h8*)(aggx + ((size_t)h * n + node) * 256 + k8 * 8) = o;
}

// ---------------- CSR build ----------------
__global__ void count_deg_k(const int* __restrict__ ei, int* __restrict__ deg, int Ereal, int Etot) {
  int e = blockIdx.x * 256 + threadIdx.x;
  if (e >= Etot) return;
  int dst = (e < Ereal) ? ei[Ereal + e] : (e - Ereal);
  atomicAdd(&deg[dst], 1);
}

__global__ void scan_k(const int* __restrict__ deg, int* __restrict__ rowptr, int n) {
  __shared__ int sums[1024];
  int t = threadIdx.x;
  int base = t * 10;
  int loc[10]; int s = 0;
#pragma unroll
  for (int i = 0; i < 10; ++i) { int idx = base + i; int d = (idx < n) ? deg[idx] : 0; loc[i] = s; s += d; }
  sums[t] = s;
  __syncthreads();
  for (int off = 1; off < 1024; off <<= 1) {
    int add = (t >= off) ? sums[t - off] : 0;
    __syncthreads();
    sums[t] += add;
    __syncthreads();
  }
  int excl = sums[t] - s;
#pragma unroll
  for (int i = 0; i < 10; ++i) { int idx = base + i; if (idx < n) rowptr[idx] = excl + loc[i]; }
  if (t == 1023) rowptr[n] = sums[1023];
}

__global__ void scatter_k(const int* __restrict__ ei, const int* __restrict__ rowptr,
                          int* __restrict__ fill, int* __restrict__ esrc,
                          int Ereal, int Etot) {
  int e = blockIdx.x * 256 + threadIdx.x;
  if (e >= Etot) return;
  int src = (e < Ereal) ? ei[e] : (e - Ereal);
  int dst = (e < Ereal) ? ei[Ereal + e] : (e - Ereal);
  int pos = rowptr[dst] + atomicAdd(&fill[dst], 1);
  esrc[pos] = src;
}

// ---------------- aggregation + fused edge-softmax (CSR, no atomics) ----------------
template <int H, bool FP32OUT, bool STATS>
__global__ __launch_bounds__(256) void aggregate_k(
    const unsigned short* __restrict__ hfp,
    const float* __restrict__ als, const float* __restrict__ ald,
    const int* __restrict__ rowptr, const int* __restrict__ esrc,
    const float* __restrict__ bias, void* __restrict__ outv,
    float* __restrict__ lnsums, int C, int F) {
  const int node = blockIdx.x;
  const int tid = threadIdx.x;
  int beg = rowptr[node];
  int deg = rowptr[node + 1] - beg;
  if (deg > 128) deg = 128;
  __shared__ int   s_src[128];
  __shared__ float s_p[128][H];
  __shared__ float s_inv[H];
  float aldv[H];
#pragma unroll
  for (int h = 0; h < H; ++h) aldv[h] = ald[node * H + h];
  for (int d = tid; d < deg; d += 256) {
    int s = esrc[beg + d];
    s_src[d] = s;
#pragma unroll
    for (int h = 0; h < H; ++h) {
      float v = als[s * H + h] + aldv[h];
      s_p[d][h] = (v >= 0.f) ? v : 0.2f * v;
    }
  }
  __syncthreads();
  if (tid < H) {
    float m = -1e30f;
    for (int d = 0; d < deg; ++d) m = fmaxf(m, s_p[d][tid]);
    float s = 0.f;
    for (int d = 0; d < deg; ++d) { float p = __expf(s_p[d][tid] - m); s_p[d][tid] = p; s += p; }
    s_inv[tid] = 1.f / (s + 1e-16f);
  }
  __syncthreads();

  float s1 = 0.f, s2 = 0.f;
  const int F8 = F >> 3;
  for (int c8 = tid; c8 < F8; c8 += 256) {
    int f0 = c8 * 8;
    int h = f0 / C;
    float a[8];
    float4 b0 = *(const float4*)(bias + f0);
    float4 b1 = *(const float4*)(bias + f0 + 4);
    a[0] = b0.x; a[1] = b0.y; a[2] = b0.z; a[3] = b0.w;
    a[4] = b1.x; a[5] = b1.y; a[6] = b1.z; a[7] = b1.w;
    for (int d = 0; d < deg; ++d) {
      float al = s_p[d][h] * s_inv[h];
      h8 hv = *(const h8*)(hfp + (size_t)s_src[d] * F + f0);
#pragma unroll
      for (int j = 0; j < 8; ++j) a[j] = fmaf(al, (float)hv[j], a[j]);
    }
    if (STATS) {
#pragma unroll
      for (int j = 0; j < 8; ++j) { float v = a[j] > 0.f ? a[j] : 0.f; a[j] = v; s1 += v; s2 += v * v; }
    }
    size_t i = (size_t)node * F + f0;
    if (FP32OUT) {
      float4 o0 = {a[0], a[1], a[2], a[3]};
      float4 o1 = {a[4], a[5], a[6], a[7]};
      *(float4*)((float*)outv + i) = o0;
      *(float4*)((float*)outv + i + 4) = o1;
    } else {
      h8 o;
#pragma unroll
      for (int j = 0; j < 8; ++j) o[j] = (_Float16)a[j];
      *(h8*)((unsigned short*)outv + i) = o;
    }
  }
  if (STATS) {
#pragma unroll
    for (int m = 32; m; m >>= 1) { s1 += __shfl_down(s1, m); s2 += __shfl_down(s2, m); }
    __shared__ float r1[4], r2[4];
    if ((tid & 63) == 0) { r1[tid >> 6] = s1; r2[tid >> 6] = s2; }
    __syncthreads();
    if (tid == 0) {
      atomicAdd(&lnsums[0], r1[0] + r1[1] + r1[2] + r1[3]);
      atomicAdd(&lnsums[1], r2[0] + r2[1] + r2[2] + r2[3]);
    }
  }
}

// ---------------- host orchestration ----------------
extern "C" void kernel_launch(void* const* d_in, const int* in_sizes, int n_in,
                              void* d_out, int out_size, void* d_ws, size_t ws_size,
                              hipStream_t stream) {
  const int N = 10000, Ereal = 50000, Etot = 60000;
  const float* x  = (const float*)d_in[0];
  const int*   ei = (const int*)d_in[1];
  const float* W[4]    = {(const float*)d_in[2],  (const float*)d_in[8],  (const float*)d_in[14], (const float*)d_in[20]};
  const float* asrc[4] = {(const float*)d_in[3],  (const float*)d_in[9],  (const float*)d_in[15], (const float*)d_in[21]};
  const float* adst[4] = {(const float*)d_in[4],  (const float*)d_in[10], (const float*)d_in[16], (const float*)d_in[22]};
  const float* bias[4] = {(const float*)d_in[5],  (const float*)d_in[11], (const float*)d_in[17], (const float*)d_in[23]};
  const float* lnw[3]  = {(const float*)d_in[6],  (const float*)d_in[12], (const float*)d_in[18]};
  const float* lnb[3]  = {(const float*)d_in[7],  (const float*)d_in[13], (const float*)d_in[19]};

  const int fin[4]  = {256, 3584, 3072, 2048};
  const int fout[4] = {3584, 3072, 2048, 1000};
  const int CH[4]   = {448, 384, 256, 1000};

  // workspace carve-up (~170 MB total)
  size_t off = 0;
  char* base = (char*)d_ws;
  auto alloc = [&](size_t bytes) -> void* {
    void* p = base + off;
    off += (bytes + 255) & ~(size_t)255;
    return p;
  };
  unsigned short* xh  = (unsigned short*)alloc((size_t)N * 3584 * 2);
  unsigned short* hh  = (unsigned short*)alloc((size_t)N * 3584 * 2);   // aliases aggx in L1
  unsigned short* wh  = (unsigned short*)alloc((size_t)3072 * 3584 * 2);
  float*          alsA   = (float*)alloc((size_t)4 * N * 8 * 4);        // contiguous: alsA|aldA|lnsA (one memset)
  float*          aldA   = (float*)alloc((size_t)4 * N * 8 * 4);
  float*          lnsA   = (float*)alloc(256);                          // 4 slots x 2 floats
  int*            deg    = (int*)alloc((size_t)N * 4);
  int*            fill   = (int*)alloc((size_t)N * 4);
  int*            rowptr = (int*)alloc((size_t)(N + 1) * 4);
  int*            esrc   = (int*)alloc((size_t)Etot * 4);
  float*          wsrc   = (float*)alloc((size_t)8 * 256 * 4);
  float*          wdst   = (float*)alloc((size_t)8 * 256 * 4);
  float*          cvec   = (float*)alloc((size_t)3072 * 4);

  auto cdiv = [](int a, int b) { return (a + b - 1) / b; };

  // --- CSR build + one-shot zero of logit accumulators and LN-stat slots ---
  hipMemsetAsync(deg, 0, (size_t)N * 4, stream);
  hipMemsetAsync(fill, 0, (size_t)N * 4, stream);
  hipMemsetAsync(alsA, 0, (size_t)4 * N * 8 * 4 * 2 + 256, stream);
  count_deg_k<<<cdiv(Etot, 256), 256, 0, stream>>>(ei, deg, Ereal, Etot);
  scan_k<<<1, 1024, 0, stream>>>(deg, rowptr, N);
  scatter_k<<<cdiv(Etot, 256), 256, 0, stream>>>(ei, rowptr, fill, esrc, Ereal, Etot);

  // --- input features -> fp16 ---
  {
    int n4 = (N * fin[0]) / 4;
    f2h_k<<<min(2048, cdiv(n4, 256)), 256, 0, stream>>>(x, xh, n4);
  }

  // ================= layer 1 (x-space aggregation: K=256 << Fo=3584) =================
  {
    float* als = alsA;
    float* ald = aldA;
    attw_k<<<8, 256, 0, stream>>>(W[0], asrc[0], adst[0], wsrc, wdst, 448, 256);
    logits_x_k<<<cdiv(N, 4), 256, 0, stream>>>(x, wsrc, wdst, als, ald, N);
    {
      int n4 = (3584 * 256) / 4;
      f2h_k<<<min(2048, cdiv(n4, 256)), 256, 0, stream>>>(W[0], wh, n4);
    }
    aggregate_x_k<<<N, 256, 0, stream>>>(xh, als, ald, rowptr, esrc, hh, N);
    // per-head GEMM: xh = relu(aggx @ W1^T + b1), LN1 stats -> slot 0
    {
      int gx = cdiv(448, 128), gy = cdiv(N, 128);
      int nwg = gx * gy;
      gemm_f16_hd<<<dim3(nwg, 8), 256, 0, stream>>>(hh, wh, xh, bias[0], lnsA,
                                                    N, 256, 3584, 448, gx, nwg);
    }
  }

  // ================= layers 2-4 (h-space aggregation, folded-LN weights) =================
  for (int l = 1; l < 4; ++l) {
    const int K = fin[l], Fo = fout[l], C = CH[l];
    const int H = (l == 3) ? 1 : 8;
    float* als = alsA + (size_t)l * N * 8;
    float* ald = aldA + (size_t)l * N * 8;

    // LN-folded weights: wh = W*istd*lnw, cvec[o] = sum_f t[f]*W[o,f]
    w2h_fold_k<<<Fo, 256, 0, stream>>>(W[l], lnw[l - 1], lnb[l - 1], lnsA + (l - 1) * 2,
                                       1.0f / (float)(N * fin[l]), wh, cvec, K);

    // GEMM + c add + fused logits: hh[N,Fo] = xh @ wh^T + c
    {
      int gx = cdiv(Fo, 128), gy = cdiv(N, 128);
      int nwg = gx * gy;
      gemm_f16<<<nwg, 256, 0, stream>>>(xh, wh, hh, als, ald, asrc[l], adst[l], cvec,
                                        N, Fo, K, C, H, gx, nwg);
    }

    // aggregate + fused softmax (+ relu + LN stats for layers 2-3)
    if (l < 3) {
      aggregate_k<8, false, true><<<N, 256, 0, stream>>>(hh, als, ald, rowptr, esrc,
                                                         bias[l], xh, lnsA + l * 2, C, Fo);
    } else {
      aggregate_k<1, true, false><<<N, 256, 0, stream>>>(hh, als, ald, rowptr, esrc,
                                                         bias[l], d_out, nullptr, C, Fo);
    }
  }
}